// Round 1
// baseline (1093.623 us; speedup 1.0000x reference)
//
#include <hip/hip_runtime.h>

// TGN data-collect: pure gathers. D = 172 f32 = 43 float4 per row.
static constexpr unsigned D4 = 43;

// dst[i] = a[idx[i/43]*43 + i%43] + b[same]   (node_feats + memory, fused)
__global__ void gather_add4_k(float4* __restrict__ dst,
                              const float4* __restrict__ a,
                              const float4* __restrict__ b,
                              const int* __restrict__ idx,
                              unsigned n4) {
    unsigned i = blockIdx.x * blockDim.x + threadIdx.x;
    unsigned stride = gridDim.x * blockDim.x;
    for (; i < n4; i += stride) {
        unsigned row = i / D4;                 // const divisor -> magic mul
        unsigned col = i - row * D4;
        unsigned s   = (unsigned)idx[row] * D4 + col;
        float4 va = a[s];
        float4 vb = b[s];
        dst[i] = make_float4(va.x + vb.x, va.y + vb.y, va.z + vb.z, va.w + vb.w);
    }
}

// dst[i] = a[idx[i/43]*43 + i%43]   (edge_feats gather)
__global__ void gather4_k(float4* __restrict__ dst,
                          const float4* __restrict__ a,
                          const int* __restrict__ idx,
                          unsigned n4) {
    unsigned i = blockIdx.x * blockDim.x + threadIdx.x;
    unsigned stride = gridDim.x * blockDim.x;
    for (; i < n4; i += stride) {
        unsigned row = i / D4;
        unsigned col = i - row * D4;
        unsigned s   = (unsigned)idx[row] * D4 + col;
        dst[i] = a[s];
    }
}

// deltas[i] = ts[i / TSD] - et[i];  mask[i] = (neigh[i]==0) ? 1 : 0
template <unsigned TSD>
__global__ void dm_k(float* __restrict__ deltas,
                     float* __restrict__ mask,
                     const float* __restrict__ ts,
                     const float* __restrict__ et,
                     const int* __restrict__ neigh,
                     unsigned n) {
    unsigned i = blockIdx.x * blockDim.x + threadIdx.x;
    unsigned stride = gridDim.x * blockDim.x;
    for (; i < n; i += stride) {
        deltas[i] = ts[i / TSD] - et[i];
        mask[i]   = (neigh[i] == 0) ? 1.0f : 0.0f;
    }
}

static inline unsigned grid_for(unsigned n, unsigned block, unsigned cap) {
    unsigned g = (n + block - 1) / block;
    return g < cap ? (g ? g : 1) : cap;
}

extern "C" void kernel_launch(void* const* d_in, const int* in_sizes, int n_in,
                              void* d_out, int out_size, void* d_ws, size_t ws_size,
                              hipStream_t stream) {
    const float* nf  = (const float*)d_in[0];   // node_feats  [100000,172]
    const float* ef  = (const float*)d_in[1];   // edge_feats  [1000000,172]
    const float* mem = (const float*)d_in[2];   // memory      [100000,172]
    const float* ts  = (const float*)d_in[3];   // timestamps  [4096]
    const float* et1 = (const float*)d_in[4];   // edge_times1 [4096,20]
    const float* et2 = (const float*)d_in[5];   // edge_times2 [81920,20]
    const int* srcn  = (const int*)d_in[6];     // source_nodes [4096]
    const int* nb1   = (const int*)d_in[7];     // neighbors1   [4096,20]
    const int* ei1   = (const int*)d_in[8];     // edge_idxs1   [4096,20]
    const int* nb2   = (const int*)d_in[9];     // neighbors2   [81920,20]
    const int* ei2   = (const int*)d_in[10];    // edge_idxs2   [81920,20]

    constexpr unsigned B = 4096, K = 20, Dd = 172;
    constexpr unsigned BK = B * K;              // 81920

    float* out = (float*)d_out;
    // flat offsets (floats), in reference return order
    size_t o = 0;
    float* src1 = out + o;  o += (size_t)B * Dd;        // src_feats1
    float* nf1  = out + o;  o += (size_t)BK * Dd;       // neigh_feats1
    float* ef1  = out + o;  o += (size_t)BK * Dd;       // edge_f1
    float* dl1  = out + o;  o += (size_t)BK;            // deltas1
    float* mk1  = out + o;  o += (size_t)BK;            // mask1
    float* sf2  = out + o;  o += (size_t)BK * Dd;       // src_feats2
    float* nf2  = out + o;  o += (size_t)BK * K * Dd;   // neigh_feats2
    float* ef2  = out + o;  o += (size_t)BK * K * Dd;   // edge_f2
    float* dl2  = out + o;  o += (size_t)BK * K;        // deltas2
    float* mk2  = out + o;  o += (size_t)BK * K;        // mask2

    const float4* nf4  = (const float4*)nf;
    const float4* mem4 = (const float4*)mem;
    const float4* ef4  = (const float4*)ef;

    const unsigned BLK = 256;
    const unsigned CAP = 2048;   // 8 blocks/CU x 256 CU; grid-stride the rest

    // src_feats1 = node_mem[source_nodes]            (4096 rows)
    {
        unsigned n4 = B * D4;
        gather_add4_k<<<grid_for(n4, BLK, CAP), BLK, 0, stream>>>(
            (float4*)src1, nf4, mem4, srcn, n4);
    }
    // neigh_feats1 = node_mem[neighbors1]            (81920 rows)
    {
        unsigned n4 = BK * D4;
        gather_add4_k<<<grid_for(n4, BLK, CAP), BLK, 0, stream>>>(
            (float4*)nf1, nf4, mem4, nb1, n4);
    }
    // edge_f1 = edge_feats[edge_idxs1]               (81920 rows)
    {
        unsigned n4 = BK * D4;
        gather4_k<<<grid_for(n4, BLK, CAP), BLK, 0, stream>>>(
            (float4*)ef1, ef4, ei1, n4);
    }
    // deltas1 / mask1
    dm_k<K><<<grid_for(BK, BLK, CAP), BLK, 0, stream>>>(dl1, mk1, ts, et1, nb1, BK);

    // src_feats2 = node_mem[neighbors1.flatten()]    (same gather as neigh_feats1)
    {
        unsigned n4 = BK * D4;
        gather_add4_k<<<grid_for(n4, BLK, CAP), BLK, 0, stream>>>(
            (float4*)sf2, nf4, mem4, nb1, n4);
    }
    // neigh_feats2 = node_mem[neighbors2]            (1,638,400 rows)
    {
        unsigned n4 = BK * K * D4;
        gather_add4_k<<<grid_for(n4, BLK, CAP), BLK, 0, stream>>>(
            (float4*)nf2, nf4, mem4, nb2, n4);
    }
    // edge_f2 = edge_feats[edge_idxs2]               (1,638,400 rows)
    {
        unsigned n4 = BK * K * D4;
        gather4_k<<<grid_for(n4, BLK, CAP), BLK, 0, stream>>>(
            (float4*)ef2, ef4, ei2, n4);
    }
    // deltas2 / mask2  (ts index = i / (K*K))
    dm_k<K * K><<<grid_for(BK * K, BLK, CAP), BLK, 0, stream>>>(dl2, mk2, ts, et2, nb2, BK * K);
}

// Round 2
// 908.465 us; speedup vs baseline: 1.2038x; 1.2038x over previous
//
#include <hip/hip_runtime.h>

// TGN data-collect: pure gathers. D = 172 f32 = 43 float4 per row.
static constexpr unsigned D4 = 43;

// dst[i] = a[i] + b[i]  (precompute node_mem table into workspace)
__global__ void addtab_k(float4* __restrict__ dst,
                         const float4* __restrict__ a,
                         const float4* __restrict__ b,
                         unsigned n4) {
    unsigned i = blockIdx.x * blockDim.x + threadIdx.x;
    unsigned stride = gridDim.x * blockDim.x;
    for (; i < n4; i += stride) {
        float4 va = a[i];
        float4 vb = b[i];
        dst[i] = make_float4(va.x + vb.x, va.y + vb.y, va.z + vb.z, va.w + vb.w);
    }
}

// dst[i] = a[idx[i/43]*43 + i%43]
__global__ void gather4_k(float4* __restrict__ dst,
                          const float4* __restrict__ a,
                          const int* __restrict__ idx,
                          unsigned n4) {
    unsigned i = blockIdx.x * blockDim.x + threadIdx.x;
    unsigned stride = gridDim.x * blockDim.x;
    for (; i < n4; i += stride) {
        unsigned row = i / D4;                 // const divisor -> magic mul
        unsigned col = i - row * D4;
        unsigned s   = (unsigned)idx[row] * D4 + col;
        dst[i] = a[s];
    }
}

// same gather, two destination streams (neigh_feats1 and src_feats2 are identical)
__global__ void gather4_dual_k(float4* __restrict__ dst1,
                               float4* __restrict__ dst2,
                               const float4* __restrict__ a,
                               const int* __restrict__ idx,
                               unsigned n4) {
    unsigned i = blockIdx.x * blockDim.x + threadIdx.x;
    unsigned stride = gridDim.x * blockDim.x;
    for (; i < n4; i += stride) {
        unsigned row = i / D4;
        unsigned col = i - row * D4;
        unsigned s   = (unsigned)idx[row] * D4 + col;
        float4 v = a[s];
        dst1[i] = v;
        dst2[i] = v;
    }
}

// ---- fallback (no workspace): fused two-table gathers ----
__global__ void gather_add4_k(float4* __restrict__ dst,
                              const float4* __restrict__ a,
                              const float4* __restrict__ b,
                              const int* __restrict__ idx,
                              unsigned n4) {
    unsigned i = blockIdx.x * blockDim.x + threadIdx.x;
    unsigned stride = gridDim.x * blockDim.x;
    for (; i < n4; i += stride) {
        unsigned row = i / D4;
        unsigned col = i - row * D4;
        unsigned s   = (unsigned)idx[row] * D4 + col;
        float4 va = a[s];
        float4 vb = b[s];
        dst[i] = make_float4(va.x + vb.x, va.y + vb.y, va.z + vb.z, va.w + vb.w);
    }
}

__global__ void gather_add4_dual_k(float4* __restrict__ dst1,
                                   float4* __restrict__ dst2,
                                   const float4* __restrict__ a,
                                   const float4* __restrict__ b,
                                   const int* __restrict__ idx,
                                   unsigned n4) {
    unsigned i = blockIdx.x * blockDim.x + threadIdx.x;
    unsigned stride = gridDim.x * blockDim.x;
    for (; i < n4; i += stride) {
        unsigned row = i / D4;
        unsigned col = i - row * D4;
        unsigned s   = (unsigned)idx[row] * D4 + col;
        float4 va = a[s];
        float4 vb = b[s];
        float4 v = make_float4(va.x + vb.x, va.y + vb.y, va.z + vb.z, va.w + vb.w);
        dst1[i] = v;
        dst2[i] = v;
    }
}

// deltas[i] = ts[i / TSD] - et[i];  mask[i] = (neigh[i]==0) ? 1 : 0
template <unsigned TSD>
__global__ void dm_k(float* __restrict__ deltas,
                     float* __restrict__ mask,
                     const float* __restrict__ ts,
                     const float* __restrict__ et,
                     const int* __restrict__ neigh,
                     unsigned n) {
    unsigned i = blockIdx.x * blockDim.x + threadIdx.x;
    unsigned stride = gridDim.x * blockDim.x;
    for (; i < n; i += stride) {
        deltas[i] = ts[i / TSD] - et[i];
        mask[i]   = (neigh[i] == 0) ? 1.0f : 0.0f;
    }
}

static inline unsigned grid_for(unsigned n, unsigned block, unsigned cap) {
    unsigned g = (n + block - 1) / block;
    return g < cap ? (g ? g : 1) : cap;
}

extern "C" void kernel_launch(void* const* d_in, const int* in_sizes, int n_in,
                              void* d_out, int out_size, void* d_ws, size_t ws_size,
                              hipStream_t stream) {
    const float* nf  = (const float*)d_in[0];   // node_feats  [100000,172]
    const float* ef  = (const float*)d_in[1];   // edge_feats  [1000000,172]
    const float* mem = (const float*)d_in[2];   // memory      [100000,172]
    const float* ts  = (const float*)d_in[3];   // timestamps  [4096]
    const float* et1 = (const float*)d_in[4];   // edge_times1 [4096,20]
    const float* et2 = (const float*)d_in[5];   // edge_times2 [81920,20]
    const int* srcn  = (const int*)d_in[6];     // source_nodes [4096]
    const int* nb1   = (const int*)d_in[7];     // neighbors1   [4096,20]
    const int* ei1   = (const int*)d_in[8];     // edge_idxs1   [4096,20]
    const int* nb2   = (const int*)d_in[9];     // neighbors2   [81920,20]
    const int* ei2   = (const int*)d_in[10];    // edge_idxs2   [81920,20]

    constexpr unsigned B = 4096, K = 20, Dd = 172;
    constexpr unsigned BK = B * K;              // 81920
    constexpr unsigned NN = 100000;

    float* out = (float*)d_out;
    size_t o = 0;
    float* src1 = out + o;  o += (size_t)B * Dd;        // src_feats1
    float* nf1  = out + o;  o += (size_t)BK * Dd;       // neigh_feats1
    float* ef1  = out + o;  o += (size_t)BK * Dd;       // edge_f1
    float* dl1  = out + o;  o += (size_t)BK;            // deltas1
    float* mk1  = out + o;  o += (size_t)BK;            // mask1
    float* sf2  = out + o;  o += (size_t)BK * Dd;       // src_feats2
    float* nf2  = out + o;  o += (size_t)BK * K * Dd;   // neigh_feats2
    float* ef2  = out + o;  o += (size_t)BK * K * Dd;   // edge_f2
    float* dl2  = out + o;  o += (size_t)BK * K;        // deltas2
    float* mk2  = out + o;  o += (size_t)BK * K;        // mask2

    const float4* nf4  = (const float4*)nf;
    const float4* mem4 = (const float4*)mem;
    const float4* ef4  = (const float4*)ef;

    const unsigned BLK = 256;
    const unsigned CAP = 2048;   // 8 blocks/CU x 256 CU; grid-stride the rest

    const size_t NM_BYTES = (size_t)NN * Dd * sizeof(float);   // 68.8 MB

    if (ws_size >= NM_BYTES) {
        // ---- path A: precompute node_mem table once per call ----
        float4* nm4 = (float4*)d_ws;
        {
            unsigned n4 = NN * D4;
            addtab_k<<<grid_for(n4, BLK, CAP), BLK, 0, stream>>>(nm4, nf4, mem4, n4);
        }
        // src_feats1
        {
            unsigned n4 = B * D4;
            gather4_k<<<grid_for(n4, BLK, CAP), BLK, 0, stream>>>(
                (float4*)src1, nm4, srcn, n4);
        }
        // neigh_feats1 + src_feats2 (identical data, dual store)
        {
            unsigned n4 = BK * D4;
            gather4_dual_k<<<grid_for(n4, BLK, CAP), BLK, 0, stream>>>(
                (float4*)nf1, (float4*)sf2, nm4, nb1, n4);
        }
        // edge_f1
        {
            unsigned n4 = BK * D4;
            gather4_k<<<grid_for(n4, BLK, CAP), BLK, 0, stream>>>(
                (float4*)ef1, ef4, ei1, n4);
        }
        dm_k<K><<<grid_for(BK, BLK, CAP), BLK, 0, stream>>>(dl1, mk1, ts, et1, nb1, BK);
        // neigh_feats2
        {
            unsigned n4 = BK * K * D4;
            gather4_k<<<grid_for(n4, BLK, CAP), BLK, 0, stream>>>(
                (float4*)nf2, nm4, nb2, n4);
        }
        // edge_f2
        {
            unsigned n4 = BK * K * D4;
            gather4_k<<<grid_for(n4, BLK, CAP), BLK, 0, stream>>>(
                (float4*)ef2, ef4, ei2, n4);
        }
        dm_k<K * K><<<grid_for(BK * K, BLK, CAP), BLK, 0, stream>>>(
            dl2, mk2, ts, et2, nb2, BK * K);
    } else {
        // ---- path B fallback: fused two-table gathers (R1 behavior + dual store) ----
        {
            unsigned n4 = B * D4;
            gather_add4_k<<<grid_for(n4, BLK, CAP), BLK, 0, stream>>>(
                (float4*)src1, nf4, mem4, srcn, n4);
        }
        {
            unsigned n4 = BK * D4;
            gather_add4_dual_k<<<grid_for(n4, BLK, CAP), BLK, 0, stream>>>(
                (float4*)nf1, (float4*)sf2, nf4, mem4, nb1, n4);
        }
        {
            unsigned n4 = BK * D4;
            gather4_k<<<grid_for(n4, BLK, CAP), BLK, 0, stream>>>(
                (float4*)ef1, ef4, ei1, n4);
        }
        dm_k<K><<<grid_for(BK, BLK, CAP), BLK, 0, stream>>>(dl1, mk1, ts, et1, nb1, BK);
        {
            unsigned n4 = BK * K * D4;
            gather_add4_k<<<grid_for(n4, BLK, CAP), BLK, 0, stream>>>(
                (float4*)nf2, nf4, mem4, nb2, n4);
        }
        {
            unsigned n4 = BK * K * D4;
            gather4_k<<<grid_for(n4, BLK, CAP), BLK, 0, stream>>>(
                (float4*)ef2, ef4, ei2, n4);
        }
        dm_k<K * K><<<grid_for(BK * K, BLK, CAP), BLK, 0, stream>>>(
            dl2, mk2, ts, et2, nb2, BK * K);
    }
}

// Round 3
// 804.828 us; speedup vs baseline: 1.3588x; 1.1288x over previous
//
#include <hip/hip_runtime.h>

// TGN data-collect: pure gathers. D = 172 f32 = 43 float4 per row.
typedef float f32x4 __attribute__((ext_vector_type(4)));

static constexpr unsigned D4 = 43;

__device__ __forceinline__ void nt_store4(f32x4* p, f32x4 v) {
    __builtin_nontemporal_store(v, p);
}

// nm[i] = a[i] + b[i]  (precompute node_mem table into workspace; NORMAL stores —
// we want this table L3-resident for the node gathers that follow)
__global__ void addtab_k(f32x4* __restrict__ dst,
                         const f32x4* __restrict__ a,
                         const f32x4* __restrict__ b,
                         unsigned n4) {
    unsigned i = blockIdx.x * blockDim.x + threadIdx.x;
    unsigned stride = gridDim.x * blockDim.x;
    for (; i < n4; i += stride) {
        dst[i] = a[i] + b[i];
    }
}

// dst[i] = a[idx[i/43]*43 + i%43]   (nt store: output has zero reuse)
__global__ void gather4_k(f32x4* __restrict__ dst,
                          const f32x4* __restrict__ a,
                          const int* __restrict__ idx,
                          unsigned n4) {
    unsigned i = blockIdx.x * blockDim.x + threadIdx.x;
    unsigned stride = gridDim.x * blockDim.x;
    for (; i < n4; i += stride) {
        unsigned row = i / D4;                 // const divisor -> magic mul
        unsigned col = i - row * D4;
        unsigned s   = (unsigned)idx[row] * D4 + col;
        nt_store4(dst + i, a[s]);
    }
}

// same gather, two destination streams (neigh_feats1 and src_feats2 are identical)
__global__ void gather4_dual_k(f32x4* __restrict__ dst1,
                               f32x4* __restrict__ dst2,
                               const f32x4* __restrict__ a,
                               const int* __restrict__ idx,
                               unsigned n4) {
    unsigned i = blockIdx.x * blockDim.x + threadIdx.x;
    unsigned stride = gridDim.x * blockDim.x;
    for (; i < n4; i += stride) {
        unsigned row = i / D4;
        unsigned col = i - row * D4;
        unsigned s   = (unsigned)idx[row] * D4 + col;
        f32x4 v = a[s];
        nt_store4(dst1 + i, v);
        nt_store4(dst2 + i, v);
    }
}

// ---- fallback (no workspace): fused two-table gathers ----
__global__ void gather_add4_k(f32x4* __restrict__ dst,
                              const f32x4* __restrict__ a,
                              const f32x4* __restrict__ b,
                              const int* __restrict__ idx,
                              unsigned n4) {
    unsigned i = blockIdx.x * blockDim.x + threadIdx.x;
    unsigned stride = gridDim.x * blockDim.x;
    for (; i < n4; i += stride) {
        unsigned row = i / D4;
        unsigned col = i - row * D4;
        unsigned s   = (unsigned)idx[row] * D4 + col;
        nt_store4(dst + i, a[s] + b[s]);
    }
}

__global__ void gather_add4_dual_k(f32x4* __restrict__ dst1,
                                   f32x4* __restrict__ dst2,
                                   const f32x4* __restrict__ a,
                                   const f32x4* __restrict__ b,
                                   const int* __restrict__ idx,
                                   unsigned n4) {
    unsigned i = blockIdx.x * blockDim.x + threadIdx.x;
    unsigned stride = gridDim.x * blockDim.x;
    for (; i < n4; i += stride) {
        unsigned row = i / D4;
        unsigned col = i - row * D4;
        unsigned s   = (unsigned)idx[row] * D4 + col;
        f32x4 v = a[s] + b[s];
        nt_store4(dst1 + i, v);
        nt_store4(dst2 + i, v);
    }
}

// deltas[i] = ts[i / TSD] - et[i];  mask[i] = (neigh[i]==0) ? 1 : 0
template <unsigned TSD>
__global__ void dm_k(float* __restrict__ deltas,
                     float* __restrict__ mask,
                     const float* __restrict__ ts,
                     const float* __restrict__ et,
                     const int* __restrict__ neigh,
                     unsigned n) {
    unsigned i = blockIdx.x * blockDim.x + threadIdx.x;
    unsigned stride = gridDim.x * blockDim.x;
    for (; i < n; i += stride) {
        __builtin_nontemporal_store(ts[i / TSD] - et[i], deltas + i);
        __builtin_nontemporal_store((neigh[i] == 0) ? 1.0f : 0.0f, mask + i);
    }
}

static inline unsigned grid_for(unsigned n, unsigned block, unsigned cap) {
    unsigned g = (n + block - 1) / block;
    return g < cap ? (g ? g : 1) : cap;
}

extern "C" void kernel_launch(void* const* d_in, const int* in_sizes, int n_in,
                              void* d_out, int out_size, void* d_ws, size_t ws_size,
                              hipStream_t stream) {
    const float* nf  = (const float*)d_in[0];   // node_feats  [100000,172]
    const float* ef  = (const float*)d_in[1];   // edge_feats  [1000000,172]
    const float* mem = (const float*)d_in[2];   // memory      [100000,172]
    const float* ts  = (const float*)d_in[3];   // timestamps  [4096]
    const float* et1 = (const float*)d_in[4];   // edge_times1 [4096,20]
    const float* et2 = (const float*)d_in[5];   // edge_times2 [81920,20]
    const int* srcn  = (const int*)d_in[6];     // source_nodes [4096]
    const int* nb1   = (const int*)d_in[7];     // neighbors1   [4096,20]
    const int* ei1   = (const int*)d_in[8];     // edge_idxs1   [4096,20]
    const int* nb2   = (const int*)d_in[9];     // neighbors2   [81920,20]
    const int* ei2   = (const int*)d_in[10];    // edge_idxs2   [81920,20]

    constexpr unsigned B = 4096, K = 20, Dd = 172;
    constexpr unsigned BK = B * K;              // 81920
    constexpr unsigned NN = 100000;

    float* out = (float*)d_out;
    size_t o = 0;
    float* src1 = out + o;  o += (size_t)B * Dd;        // src_feats1
    float* nf1  = out + o;  o += (size_t)BK * Dd;       // neigh_feats1
    float* ef1  = out + o;  o += (size_t)BK * Dd;       // edge_f1
    float* dl1  = out + o;  o += (size_t)BK;            // deltas1
    float* mk1  = out + o;  o += (size_t)BK;            // mask1
    float* sf2  = out + o;  o += (size_t)BK * Dd;       // src_feats2
    float* nf2  = out + o;  o += (size_t)BK * K * Dd;   // neigh_feats2
    float* ef2  = out + o;  o += (size_t)BK * K * Dd;   // edge_f2
    float* dl2  = out + o;  o += (size_t)BK * K;        // deltas2
    float* mk2  = out + o;  o += (size_t)BK * K;        // mask2

    const f32x4* nf4  = (const f32x4*)nf;
    const f32x4* mem4 = (const f32x4*)mem;
    const f32x4* ef4  = (const f32x4*)ef;

    const unsigned BLK = 256;
    const unsigned CAP = 2048;   // 8 blocks/CU x 256 CU; grid-stride the rest

    const size_t NM_BYTES = (size_t)NN * Dd * sizeof(float);   // 68.8 MB

    if (ws_size >= NM_BYTES) {
        // ---- path A: precompute node_mem once; node gathers while nm is L3-hot;
        //      edge gathers last (their 688 MB stream may evict nm harmlessly) ----
        f32x4* nm4 = (f32x4*)d_ws;
        {
            unsigned n4 = NN * D4;
            addtab_k<<<grid_for(n4, BLK, CAP), BLK, 0, stream>>>(nm4, nf4, mem4, n4);
        }
        // src_feats1
        {
            unsigned n4 = B * D4;
            gather4_k<<<grid_for(n4, BLK, CAP), BLK, 0, stream>>>(
                (f32x4*)src1, nm4, srcn, n4);
        }
        // neigh_feats1 + src_feats2 (identical data, dual store)
        {
            unsigned n4 = BK * D4;
            gather4_dual_k<<<grid_for(n4, BLK, CAP), BLK, 0, stream>>>(
                (f32x4*)nf1, (f32x4*)sf2, nm4, nb1, n4);
        }
        // neigh_feats2 (the big node gather — nm still hot)
        {
            unsigned n4 = BK * K * D4;
            gather4_k<<<grid_for(n4, BLK, CAP), BLK, 0, stream>>>(
                (f32x4*)nf2, nm4, nb2, n4);
        }
        // deltas/masks (tiny)
        dm_k<K><<<grid_for(BK, BLK, CAP), BLK, 0, stream>>>(dl1, mk1, ts, et1, nb1, BK);
        dm_k<K * K><<<grid_for(BK * K, BLK, CAP), BLK, 0, stream>>>(
            dl2, mk2, ts, et2, nb2, BK * K);
        // edge_f1
        {
            unsigned n4 = BK * D4;
            gather4_k<<<grid_for(n4, BLK, CAP), BLK, 0, stream>>>(
                (f32x4*)ef1, ef4, ei1, n4);
        }
        // edge_f2
        {
            unsigned n4 = BK * K * D4;
            gather4_k<<<grid_for(n4, BLK, CAP), BLK, 0, stream>>>(
                (f32x4*)ef2, ef4, ei2, n4);
        }
    } else {
        // ---- path B fallback: fused two-table gathers, same ordering ----
        {
            unsigned n4 = B * D4;
            gather_add4_k<<<grid_for(n4, BLK, CAP), BLK, 0, stream>>>(
                (f32x4*)src1, nf4, mem4, srcn, n4);
        }
        {
            unsigned n4 = BK * D4;
            gather_add4_dual_k<<<grid_for(n4, BLK, CAP), BLK, 0, stream>>>(
                (f32x4*)nf1, (f32x4*)sf2, nf4, mem4, nb1, n4);
        }
        {
            unsigned n4 = BK * K * D4;
            gather_add4_k<<<grid_for(n4, BLK, CAP), BLK, 0, stream>>>(
                (f32x4*)nf2, nf4, mem4, nb2, n4);
        }
        dm_k<K><<<grid_for(BK, BLK, CAP), BLK, 0, stream>>>(dl1, mk1, ts, et1, nb1, BK);
        dm_k<K * K><<<grid_for(BK * K, BLK, CAP), BLK, 0, stream>>>(
            dl2, mk2, ts, et2, nb2, BK * K);
        {
            unsigned n4 = BK * D4;
            gather4_k<<<grid_for(n4, BLK, CAP), BLK, 0, stream>>>(
                (f32x4*)ef1, ef4, ei1, n4);
        }
        {
            unsigned n4 = BK * K * D4;
            gather4_k<<<grid_for(n4, BLK, CAP), BLK, 0, stream>>>(
                (f32x4*)ef2, ef4, ei2, n4);
        }
    }
}

// Round 4
// 802.520 us; speedup vs baseline: 1.3627x; 1.0029x over previous
//
#include <hip/hip_runtime.h>

// TGN data-collect: pure gathers. D = 172 f32 = 43 float4 per row.
typedef float f32x4 __attribute__((ext_vector_type(4)));

static constexpr unsigned D4 = 43;

// ============ fused path A (workspace holds node_mem table) ============

// K1: addtab (nm = nf+mem) | dm1 | dm2 | ef1   — block-range partitioned.
// addtab gets the lowest block IDs so nm is written early; none of the other
// segments depend on it.
__global__ __launch_bounds__(256) void k1_fused(
    f32x4* __restrict__ nm, const f32x4* __restrict__ nf, const f32x4* __restrict__ mem,
    float* __restrict__ dl1, float* __restrict__ mk1, const float* __restrict__ ts,
    const float* __restrict__ et1, const int* __restrict__ nb1,
    float* __restrict__ dl2, float* __restrict__ mk2,
    const float* __restrict__ et2, const int* __restrict__ nb2,
    f32x4* __restrict__ ef1o, const f32x4* __restrict__ ef, const int* __restrict__ ei1)
{
    constexpr unsigned ADD_N = 100000u * D4;          // 4,300,000
    constexpr unsigned ADD_B = (ADD_N + 255u) / 256u; // 16797 (last block partial)
    constexpr unsigned DM1_B = 81920u / 256u;         // 320
    constexpr unsigned DM2_B = 1638400u / 256u;       // 6400
    unsigned b = blockIdx.x, t = threadIdx.x;

    if (b < ADD_B) {
        unsigned i = b * 256u + t;
        if (i < ADD_N) nm[i] = nf[i] + mem[i];        // normal store: keep L3-resident
    } else if (b < ADD_B + DM1_B) {
        unsigned i = (b - ADD_B) * 256u + t;
        __builtin_nontemporal_store(ts[i / 20u] - et1[i], dl1 + i);
        __builtin_nontemporal_store((nb1[i] == 0) ? 1.0f : 0.0f, mk1 + i);
    } else if (b < ADD_B + DM1_B + DM2_B) {
        unsigned i = (b - ADD_B - DM1_B) * 256u + t;
        __builtin_nontemporal_store(ts[i / 400u] - et2[i], dl2 + i);
        __builtin_nontemporal_store((nb2[i] == 0) ? 1.0f : 0.0f, mk2 + i);
    } else {
        unsigned i = (b - ADD_B - DM1_B - DM2_B) * 256u + t;   // EF1: 3,522,560 exact
        unsigned row = i / D4, col = i - row * D4;
        unsigned s = (unsigned)ei1[row] * D4 + col;
        __builtin_nontemporal_store(ef[s], ef1o + i);
    }
}
static constexpr unsigned K1_BLOCKS =
    ((100000u * 43u + 255u) / 256u) + (81920u / 256u) + (1638400u / 256u)
    + ((81920u * 43u) / 256u);

// K2: all node_mem gathers (src1 | nf1+sf2 dual | nf2) while nm is L3-hot.
__global__ __launch_bounds__(256) void k2_nodes(
    const f32x4* __restrict__ nm,
    f32x4* __restrict__ src1, const int* __restrict__ srcn,
    f32x4* __restrict__ nf1o, f32x4* __restrict__ sf2, const int* __restrict__ nb1,
    f32x4* __restrict__ nf2o, const int* __restrict__ nb2)
{
    constexpr unsigned S1_B = (4096u * D4) / 256u;    // 688 exact
    constexpr unsigned N1_B = (81920u * D4) / 256u;   // 13760 exact
    unsigned b = blockIdx.x, t = threadIdx.x;

    if (b < S1_B) {
        unsigned i = b * 256u + t;
        unsigned row = i / D4, col = i - row * D4;
        __builtin_nontemporal_store(nm[(unsigned)srcn[row] * D4 + col], src1 + i);
    } else if (b < S1_B + N1_B) {
        unsigned i = (b - S1_B) * 256u + t;
        unsigned row = i / D4, col = i - row * D4;
        f32x4 v = nm[(unsigned)nb1[row] * D4 + col];
        __builtin_nontemporal_store(v, nf1o + i);
        __builtin_nontemporal_store(v, sf2 + i);
    } else {
        unsigned i = (b - S1_B - N1_B) * 256u + t;    // 70,451,200 exact
        unsigned row = i / D4, col = i - row * D4;
        __builtin_nontemporal_store(nm[(unsigned)nb2[row] * D4 + col], nf2o + i);
    }
}
static constexpr unsigned K2_BLOCKS =
    ((4096u * 43u) / 256u) + ((81920u * 43u) / 256u) + ((1638400u * 43u) / 256u);

// K3: ef2 edge gather (biggest, HBM-compulsory) — last so its stream can't
// hurt the node phases.
__global__ __launch_bounds__(256) void k3_ef2(
    f32x4* __restrict__ dst, const f32x4* __restrict__ ef, const int* __restrict__ ei2)
{
    unsigned i = blockIdx.x * 256u + threadIdx.x;     // 70,451,200 exact multiple
    unsigned row = i / D4, col = i - row * D4;
    __builtin_nontemporal_store(ef[(unsigned)ei2[row] * D4 + col], dst + i);
}
static constexpr unsigned K3_BLOCKS = (1638400u * 43u) / 256u;

// ============ fallback path B (no usable workspace) ============

__global__ void gather4_k(f32x4* __restrict__ dst,
                          const f32x4* __restrict__ a,
                          const int* __restrict__ idx,
                          unsigned n4) {
    unsigned i = blockIdx.x * blockDim.x + threadIdx.x;
    unsigned stride = gridDim.x * blockDim.x;
    for (; i < n4; i += stride) {
        unsigned row = i / D4, col = i - row * D4;
        __builtin_nontemporal_store(a[(unsigned)idx[row] * D4 + col], dst + i);
    }
}

__global__ void gather_add4_k(f32x4* __restrict__ dst,
                              const f32x4* __restrict__ a,
                              const f32x4* __restrict__ b,
                              const int* __restrict__ idx,
                              unsigned n4) {
    unsigned i = blockIdx.x * blockDim.x + threadIdx.x;
    unsigned stride = gridDim.x * blockDim.x;
    for (; i < n4; i += stride) {
        unsigned row = i / D4, col = i - row * D4;
        unsigned s = (unsigned)idx[row] * D4 + col;
        __builtin_nontemporal_store(a[s] + b[s], dst + i);
    }
}

__global__ void gather_add4_dual_k(f32x4* __restrict__ dst1,
                                   f32x4* __restrict__ dst2,
                                   const f32x4* __restrict__ a,
                                   const f32x4* __restrict__ b,
                                   const int* __restrict__ idx,
                                   unsigned n4) {
    unsigned i = blockIdx.x * blockDim.x + threadIdx.x;
    unsigned stride = gridDim.x * blockDim.x;
    for (; i < n4; i += stride) {
        unsigned row = i / D4, col = i - row * D4;
        unsigned s = (unsigned)idx[row] * D4 + col;
        f32x4 v = a[s] + b[s];
        __builtin_nontemporal_store(v, dst1 + i);
        __builtin_nontemporal_store(v, dst2 + i);
    }
}

template <unsigned TSD>
__global__ void dm_k(float* __restrict__ deltas,
                     float* __restrict__ mask,
                     const float* __restrict__ ts,
                     const float* __restrict__ et,
                     const int* __restrict__ neigh,
                     unsigned n) {
    unsigned i = blockIdx.x * blockDim.x + threadIdx.x;
    unsigned stride = gridDim.x * blockDim.x;
    for (; i < n; i += stride) {
        __builtin_nontemporal_store(ts[i / TSD] - et[i], deltas + i);
        __builtin_nontemporal_store((neigh[i] == 0) ? 1.0f : 0.0f, mask + i);
    }
}

static inline unsigned grid_for(unsigned n, unsigned block, unsigned cap) {
    unsigned g = (n + block - 1) / block;
    return g < cap ? (g ? g : 1) : cap;
}

extern "C" void kernel_launch(void* const* d_in, const int* in_sizes, int n_in,
                              void* d_out, int out_size, void* d_ws, size_t ws_size,
                              hipStream_t stream) {
    const float* nf  = (const float*)d_in[0];   // node_feats  [100000,172]
    const float* ef  = (const float*)d_in[1];   // edge_feats  [1000000,172]
    const float* mem = (const float*)d_in[2];   // memory      [100000,172]
    const float* ts  = (const float*)d_in[3];   // timestamps  [4096]
    const float* et1 = (const float*)d_in[4];   // edge_times1 [4096,20]
    const float* et2 = (const float*)d_in[5];   // edge_times2 [81920,20]
    const int* srcn  = (const int*)d_in[6];     // source_nodes [4096]
    const int* nb1   = (const int*)d_in[7];     // neighbors1   [4096,20]
    const int* ei1   = (const int*)d_in[8];     // edge_idxs1   [4096,20]
    const int* nb2   = (const int*)d_in[9];     // neighbors2   [81920,20]
    const int* ei2   = (const int*)d_in[10];    // edge_idxs2   [81920,20]

    constexpr unsigned B = 4096, K = 20, Dd = 172;
    constexpr unsigned BK = B * K;              // 81920
    constexpr unsigned NN = 100000;

    float* out = (float*)d_out;
    size_t o = 0;
    float* src1 = out + o;  o += (size_t)B * Dd;        // src_feats1
    float* nf1  = out + o;  o += (size_t)BK * Dd;       // neigh_feats1
    float* ef1  = out + o;  o += (size_t)BK * Dd;       // edge_f1
    float* dl1  = out + o;  o += (size_t)BK;            // deltas1
    float* mk1  = out + o;  o += (size_t)BK;            // mask1
    float* sf2  = out + o;  o += (size_t)BK * Dd;       // src_feats2
    float* nf2  = out + o;  o += (size_t)BK * K * Dd;   // neigh_feats2
    float* ef2  = out + o;  o += (size_t)BK * K * Dd;   // edge_f2
    float* dl2  = out + o;  o += (size_t)BK * K;        // deltas2
    float* mk2  = out + o;  o += (size_t)BK * K;        // mask2

    const f32x4* nf4  = (const f32x4*)nf;
    const f32x4* mem4 = (const f32x4*)mem;
    const f32x4* ef4  = (const f32x4*)ef;

    const size_t NM_BYTES = (size_t)NN * Dd * sizeof(float);   // 68.8 MB

    if (ws_size >= NM_BYTES) {
        f32x4* nm4 = (f32x4*)d_ws;
        k1_fused<<<K1_BLOCKS, 256, 0, stream>>>(
            nm4, nf4, mem4,
            dl1, mk1, ts, et1, nb1,
            dl2, mk2, et2, nb2,
            (f32x4*)ef1, ef4, ei1);
        k2_nodes<<<K2_BLOCKS, 256, 0, stream>>>(
            nm4,
            (f32x4*)src1, srcn,
            (f32x4*)nf1, (f32x4*)sf2, nb1,
            (f32x4*)nf2, nb2);
        k3_ef2<<<K3_BLOCKS, 256, 0, stream>>>((f32x4*)ef2, ef4, ei2);
    } else {
        // fallback: unfused, fused-add gathers (no nm table)
        const unsigned BLK = 256, CAP = 2048;
        {
            unsigned n4 = B * D4;
            gather_add4_k<<<grid_for(n4, BLK, CAP), BLK, 0, stream>>>(
                (f32x4*)src1, nf4, mem4, srcn, n4);
        }
        {
            unsigned n4 = BK * D4;
            gather_add4_dual_k<<<grid_for(n4, BLK, CAP), BLK, 0, stream>>>(
                (f32x4*)nf1, (f32x4*)sf2, nf4, mem4, nb1, n4);
        }
        {
            unsigned n4 = BK * K * D4;
            gather_add4_k<<<grid_for(n4, BLK, CAP), BLK, 0, stream>>>(
                (f32x4*)nf2, nf4, mem4, nb2, n4);
        }
        dm_k<K><<<grid_for(BK, BLK, CAP), BLK, 0, stream>>>(dl1, mk1, ts, et1, nb1, BK);
        dm_k<K * K><<<grid_for(BK * K, BLK, CAP), BLK, 0, stream>>>(
            dl2, mk2, ts, et2, nb2, BK * K);
        {
            unsigned n4 = BK * D4;
            gather4_k<<<grid_for(n4, BLK, CAP), BLK, 0, stream>>>(
                (f32x4*)ef1, ef4, ei1, n4);
        }
        {
            unsigned n4 = BK * K * D4;
            gather4_k<<<grid_for(n4, BLK, CAP), BLK, 0, stream>>>(
                (f32x4*)ef2, ef4, ei2, n4);
        }
    }
}